// Round 8
// baseline (56.197 us; speedup 1.0000x reference)
//
#include <hip/hip_runtime.h>

#define B 64
#define T 4096
#define AD 1024   // ATTN_RNN_DIM
#define HD 256    // HYPERNET_DIM
#define CH 32
#define KS 31
#define OD 128
#define PADW 15
#define CWN (CH*KS)   // 992
#define TILE_T 64
#define NTILE (T / TILE_T)   // 64

// ---------------- Kernel A: h[b,j] = tanh(dot(query[b,:], W1[j,:]) + b1[j])
__global__ __launch_bounds__(256) void k_hyper1(const float* __restrict__ q,
        const float* __restrict__ W1, const float* __restrict__ b1,
        float* __restrict__ h) {
    int wid  = blockIdx.x * 4 + (threadIdx.x >> 6);
    int lane = threadIdx.x & 63;
    int b = wid >> 8;
    int j = wid & 255;
    const float4* qr = (const float4*)(q  + (size_t)b * AD);
    const float4* wr = (const float4*)(W1 + (size_t)j * AD);
    float s = 0.f;
    #pragma unroll
    for (int m = 0; m < 4; ++m) {
        float4 a = qr[m * 64 + lane];
        float4 w = wr[m * 64 + lane];
        s += a.x * w.x + a.y * w.y + a.z * w.z + a.w * w.w;
    }
    #pragma unroll
    for (int off = 32; off > 0; off >>= 1)
        s += __shfl_down(s, off, 64);
    if (lane == 0) h[b * HD + j] = tanhf(s + b1[j]);
}

// ---------------- Kernel B: cw[b,r] = dot(h[b,:], W2[r,:]) + b2[r]
__global__ __launch_bounds__(256) void k_cw(const float* __restrict__ h,
        const float* __restrict__ W2, const float* __restrict__ b2,
        float* __restrict__ cw) {
    int b   = blockIdx.x >> 2;
    int qtr = blockIdx.x & 3;
    int tid = threadIdx.x;
    __shared__ float hs[HD];
    hs[tid] = h[(size_t)b * HD + tid];
    __syncthreads();
    int r = qtr * 248 + tid;
    if (tid < 248) {
        const float4* wr = (const float4*)(W2 + (size_t)r * HD);
        float s = 0.f;
        #pragma unroll
        for (int m = 0; m < HD / 4; ++m) {
            float4 w = wr[m];
            s += w.x * hs[4*m+0] + w.y * hs[4*m+1]
               + w.z * hs[4*m+2] + w.w * hs[4*m+3];
        }
        cw[(size_t)b * CWN + r] = s + b2[r];
    }
}

// ---------------- Kernel C: Gt[b, k*OD+o] = sum_c Wfc[o,c]*cw[b, c*KS+k]
__global__ __launch_bounds__(256) void k_G(const float* __restrict__ cw,
        const float* __restrict__ Wfc, float* __restrict__ Gt) {
    int b   = blockIdx.x >> 2;
    int qtr = blockIdx.x & 3;
    int tid = threadIdx.x;
    __shared__ float cws[CWN];
    __shared__ float wfs_t[CH * OD];   // [c][o]
    #pragma unroll
    for (int p = 0; p < 4; ++p) {
        int idx = p * 256 + tid;
        if (idx < CWN) cws[idx] = cw[(size_t)b * CWN + idx];
    }
    #pragma unroll
    for (int p = 0; p < 16; ++p) {
        int idx = p * 256 + tid;
        int o = idx >> 5, c = idx & 31;
        wfs_t[c * OD + o] = Wfc[idx];
    }
    __syncthreads();
    if (tid < 248) {
        int base = qtr * 992 + tid * 4;
        #pragma unroll
        for (int j = 0; j < 4; ++j) {
            int idx = base + j;
            int k = idx >> 7, o = idx & 127;
            float s = 0.f;
            #pragma unroll
            for (int c = 0; c < CH; ++c)
                s += wfs_t[c * OD + o] * cws[c * KS + k];
            Gt[(size_t)b * (KS * OD) + idx] = s;
        }
    }
}

// ---------------- Kernel D: out[b,t,o] = sum_k Gt[b,k,o]*pa[b,t+k-15] + bfc[o]
// lane owns o4 = 4 consecutive o's x 8 t-rows -> register accumulate ->
// direct float4 stores (half-wave = one full 512B row). One barrier total.
__global__ __launch_bounds__(256, 5) void k_conv(const float* __restrict__ pa_g,
        const float* __restrict__ Gt, const float* __restrict__ bfc,
        float* __restrict__ out) {
    // XCD swizzle: grid 4096 = 8 XCDs x 512; each b's 64 tiles on one XCD
    int bid  = blockIdx.x;
    int sid  = (bid & 7) * 512 + (bid >> 3);
    int b    = sid >> 6;
    int tile = sid & 63;
    int t0   = tile * TILE_T;
    int tid  = threadIdx.x;
    __shared__ float Gl[KS * OD];        // 15.5 KB, [k][o]
    __shared__ float pa[TILE_T + 32];    // 94 used

    #pragma unroll
    for (int p = 0; p < 16; ++p) {
        int idx = p * 256 + tid;
        if (idx < KS * OD) Gl[idx] = Gt[(size_t)b * (KS * OD) + idx];
    }
    if (tid < TILE_T + 30) {
        int gg = t0 + tid - PADW;
        pa[tid] = (gg >= 0 && gg < T) ? pa_g[(size_t)b * T + gg] : 0.f;
    }
    __syncthreads();

    int o4 = (tid & 31) * 4;        // 4 consecutive outputs
    int s0 = (tid >> 5) * 8;        // 8 t-rows per thread
    float4 base = *(const float4*)(bfc + o4);

    // pa window for rows s0..s0+7: pa[s0 .. s0+38); 10 aligned float4 reads
    float pw[40];
    const float4* pv = (const float4*)(pa + s0);   // s0 % 8 == 0 -> aligned
    #pragma unroll
    for (int q4 = 0; q4 < 10; ++q4) {
        float4 v = pv[q4];
        pw[q4*4+0] = v.x; pw[q4*4+1] = v.y; pw[q4*4+2] = v.z; pw[q4*4+3] = v.w;
    }

    float4 acc[8];
    #pragma unroll
    for (int r = 0; r < 8; ++r) acc[r] = base;
    #pragma unroll
    for (int k = 0; k < KS; ++k) {
        float4 gk = *(const float4*)&Gl[k * OD + o4];
        #pragma unroll
        for (int r = 0; r < 8; ++r) {
            float p = pw[r + k];
            acc[r].x += gk.x * p;
            acc[r].y += gk.y * p;
            acc[r].z += gk.z * p;
            acc[r].w += gk.w * p;
        }
    }

    // direct stores: half-wave (32 lanes x 16B) = one full 512B output row
    size_t obase = ((size_t)b * T + t0) * OD + o4;
    #pragma unroll
    for (int r = 0; r < 8; ++r)
        *(float4*)(out + obase + (size_t)(s0 + r) * OD) = acc[r];
}

extern "C" void kernel_launch(void* const* d_in, const int* in_sizes, int n_in,
                              void* d_out, int out_size, void* d_ws, size_t ws_size,
                              hipStream_t stream) {
    const float* query = (const float*)d_in[0];
    const float* prev  = (const float*)d_in[1];
    const float* W1    = (const float*)d_in[2];
    const float* b1    = (const float*)d_in[3];
    const float* W2    = (const float*)d_in[4];
    const float* b2    = (const float*)d_in[5];
    const float* Wfc   = (const float*)d_in[6];
    const float* bfc   = (const float*)d_in[7];
    float* out = (float*)d_out;

    float* h  = (float*)d_ws;          // 16384 floats
    float* cw = h + B * HD;            // 63488 floats
    float* Gt = cw + B * CWN;          // 253952 floats

    k_hyper1<<<dim3(4096), dim3(256), 0, stream>>>(query, W1, b1, h);
    k_cw    <<<dim3(B * 4), dim3(256), 0, stream>>>(h, W2, b2, cw);
    k_G     <<<dim3(B * 4), dim3(256), 0, stream>>>(cw, Wfc, Gt);
    k_conv  <<<dim3(B * NTILE), dim3(256), 0, stream>>>(prev, Gt, bfc, out);
}

// Round 9
// 53.036 us; speedup vs baseline: 1.0596x; 1.0596x over previous
//
#include <hip/hip_runtime.h>

#define B 64
#define T 4096
#define AD 1024   // ATTN_RNN_DIM
#define HD 256    // HYPERNET_DIM
#define CH 32
#define KS 31
#define OD 128
#define PADW 15
#define CWN (CH*KS)   // 992
#define TILE_T 128
#define NTILE (T / TILE_T)   // 32

// ---------------- Kernel A: h[b,j] = tanh(dot(query[b,:], W1[j,:]) + b1[j])
__global__ __launch_bounds__(256) void k_hyper1(const float* __restrict__ q,
        const float* __restrict__ W1, const float* __restrict__ b1,
        float* __restrict__ h) {
    int wid  = blockIdx.x * 4 + (threadIdx.x >> 6);
    int lane = threadIdx.x & 63;
    int b = wid >> 8;
    int j = wid & 255;
    const float4* qr = (const float4*)(q  + (size_t)b * AD);
    const float4* wr = (const float4*)(W1 + (size_t)j * AD);
    float s = 0.f;
    #pragma unroll
    for (int m = 0; m < 4; ++m) {
        float4 a = qr[m * 64 + lane];
        float4 w = wr[m * 64 + lane];
        s += a.x * w.x + a.y * w.y + a.z * w.z + a.w * w.w;
    }
    #pragma unroll
    for (int off = 32; off > 0; off >>= 1)
        s += __shfl_down(s, off, 64);
    if (lane == 0) h[b * HD + j] = tanhf(s + b1[j]);
}

// ---------------- Kernel B (fused cw+G): block (b,q) owns k in [8q, min(8q+8,31))
// computes its own cw slice {c*KS+k} into LDS, then G[k,o] for its k-range.
__global__ __launch_bounds__(256) void k_cwG(const float* __restrict__ h,
        const float* __restrict__ W2, const float* __restrict__ b2,
        const float* __restrict__ Wfc, float* __restrict__ Gt) {
    int b = blockIdx.x >> 2;
    int q = blockIdx.x & 3;
    int tid = threadIdx.x;
    __shared__ float hs[HD];           // 1 KB
    __shared__ float cwl[CH * 8];      // [c][kk], 1 KB
    __shared__ float wfs_t[CH * OD];   // [c][o], 16 KB
    hs[tid] = h[(size_t)b * HD + tid];
    #pragma unroll
    for (int p = 0; p < 16; ++p) {
        int idx = p * 256 + tid;
        int o = idx >> 5, c = idx & 31;
        wfs_t[c * OD + o] = Wfc[idx];
    }
    __syncthreads();
    {
        int c = tid >> 3, kk = tid & 7;
        int k = q * 8 + kk;
        if (k < KS) {
            int r = c * KS + k;
            const float4* wr  = (const float4*)(W2 + (size_t)r * HD);
            const float4* hs4 = (const float4*)hs;
            float s = 0.f;
            #pragma unroll
            for (int m = 0; m < HD / 4; ++m) {
                float4 w = wr[m], hv = hs4[m];
                s += w.x * hv.x + w.y * hv.y + w.z * hv.z + w.w * hv.w;
            }
            cwl[c * 8 + kk] = s + b2[r];
        }
    }
    __syncthreads();
    #pragma unroll
    for (int p = 0; p < 4; ++p) {
        int idx = p * 256 + tid;
        int kl = idx >> 7, o = idx & 127;
        int kg = q * 8 + kl;
        if (kg < KS) {
            float s = 0.f;
            #pragma unroll
            for (int c = 0; c < CH; ++c)
                s += wfs_t[c * OD + o] * cwl[c * 8 + kl];   // bcast + stride-1
            Gt[(size_t)b * (KS * OD) + kg * OD + o] = s;
        }
    }
}

// ---------------- Kernel C: out[b,t,o] = sum_k Gt[b,k,o]*pa[b,t+k-15] + bfc[o]
// R7 chunk structure (compute->barrier->wide store, pipelined), 2 passes/block
__device__ __forceinline__ void compute_chunk(const float* pa, int s0, float base,
                                              const float (&g)[KS], float (&acc)[8]) {
    float pw[40];
    const float4* lp = (const float4*)(pa + s0);   // s0 % 8 == 0 -> aligned
    #pragma unroll
    for (int q4 = 0; q4 < 10; ++q4) {
        float4 v = lp[q4];
        pw[q4*4+0] = v.x; pw[q4*4+1] = v.y; pw[q4*4+2] = v.z; pw[q4*4+3] = v.w;
    }
    #pragma unroll
    for (int tt = 0; tt < 8; ++tt) {
        float a = base;
        #pragma unroll
        for (int k = 0; k < KS; ++k)
            a += g[k] * pw[tt + k];
        acc[tt] = a;
    }
}

__global__ __launch_bounds__(256, 4) void k_conv(const float* __restrict__ pa_g,
        const float* __restrict__ Gt, const float* __restrict__ bfc,
        float* __restrict__ out) {
    // XCD swizzle: grid 2048 = 8 XCDs x 256; each XCD gets 8 whole batches
    int bid  = blockIdx.x;
    int sid  = (bid & 7) * 256 + (bid >> 3);
    int b    = sid >> 5;          // 32 tiles per b
    int tile = sid & 31;
    int t0   = tile * TILE_T;
    int tid  = threadIdx.x;
    __shared__ float tileo[64][128];      // 32 KB
    __shared__ float pa[TILE_T + 32];     // 158 used

    if (tid < TILE_T + 30) {
        int gg = t0 + tid - PADW;
        pa[tid] = (gg >= 0 && gg < T) ? pa_g[(size_t)b * T + gg] : 0.f;
    }
    int o = tid & 127, half = tid >> 7;
    float g[KS];
    #pragma unroll
    for (int k = 0; k < KS; ++k)
        g[k] = Gt[(size_t)b * (KS * OD) + k * OD + o];   // coalesced, L2-hot
    float base = bfc[o];
    __syncthreads();

    #pragma unroll
    for (int pass = 0; pass < 2; ++pass) {
        const float* pap = pa + pass * 64;               // keeps 16B alignment
        size_t obase = ((size_t)b * T + t0 + pass * 64) * OD;
        #pragma unroll
        for (int c = 0; c < 4; ++c) {
            int s0 = half * 32 + c * 8;
            float acc[8];
            compute_chunk(pap, s0, base, g, acc);
            #pragma unroll
            for (int tt = 0; tt < 8; ++tt)
                tileo[s0 + tt][o] = acc[tt];             // 2-way alias: free
            __syncthreads();
            // store the 16 completed rows, 1KB contiguous per wave-instr
            #pragma unroll
            for (int j = 0; j < 2; ++j) {
                int f  = j * 256 + tid;
                int rl = f >> 5, c4 = f & 31;
                int row = (j == 0) ? (c * 8 + rl) : (32 + c * 8 + (rl - 8));
                float4 v = *(const float4*)&tileo[row][c4 * 4];
                *(float4*)(out + obase + (size_t)row * OD + c4 * 4) = v;
            }
            // no barrier: next chunk (and next pass's chunk 0) writes
            // LDS rows disjoint from the rows just read
        }
    }
}

extern "C" void kernel_launch(void* const* d_in, const int* in_sizes, int n_in,
                              void* d_out, int out_size, void* d_ws, size_t ws_size,
                              hipStream_t stream) {
    const float* query = (const float*)d_in[0];
    const float* prev  = (const float*)d_in[1];
    const float* W1    = (const float*)d_in[2];
    const float* b1    = (const float*)d_in[3];
    const float* W2    = (const float*)d_in[4];
    const float* b2    = (const float*)d_in[5];
    const float* Wfc   = (const float*)d_in[6];
    const float* bfc   = (const float*)d_in[7];
    float* out = (float*)d_out;

    float* h  = (float*)d_ws;          // 16384 floats
    float* Gt = h + B * HD;            // 253952 floats

    k_hyper1<<<dim3(4096), dim3(256), 0, stream>>>(query, W1, b1, h);
    k_cwG   <<<dim3(B * 4), dim3(256), 0, stream>>>(h, W2, b2, Wfc, Gt);
    k_conv  <<<dim3(B * NTILE), dim3(256), 0, stream>>>(prev, Gt, bfc, out);
}